// Round 1
// baseline (150.276 us; speedup 1.0000x reference)
//
#include <hip/hip_runtime.h>
#include <hip/hip_bf16.h>

typedef __attribute__((ext_vector_type(8))) short bf16x8;
typedef __attribute__((ext_vector_type(4))) float f32x4;

#define IN 128
#define OUT 128
#define NB 8192
#define NCH 129
#define WB_CHUNK (OUT * IN)           // 16384 elements per chunk
#define SWZ(j) ((((j) >> 2) & 7) << 2)

static __device__ __forceinline__ unsigned short f2bf(float v) {
    unsigned u = __builtin_bit_cast(unsigned, v);
    unsigned r = (u + 0x7FFFu + ((u >> 16) & 1u)) >> 16;   // RNE
    return (unsigned short)r;
}

// ---- prep: WB[129][o][j] bf16 (chunk i: lc_w[o,pos(i,j)], diag=0; chunk 128: w1*scale)
// ---- plus bias[o] = sum_j translation[j]*w1[o,j]
__global__ __launch_bounds__(256) void prep_kernel(
    const float* __restrict__ lcw, const float* __restrict__ w1,
    const float* __restrict__ sc, const float* __restrict__ tr,
    __hip_bfloat16* __restrict__ WB, float* __restrict__ bias)
{
    if (blockIdx.x < 1032) {
        size_t idx = (size_t)blockIdx.x * 2048 + (size_t)threadIdx.x * 8;
        int c   = (int)(idx >> 14);
        int rem = (int)(idx & 16383);
        int o   = rem >> 7;
        int j0  = rem & 127;
        bf16x8 v;
        if (c < 128) {
            const float* lr = lcw + (size_t)o * 16256 + (size_t)c * 127;
            #pragma unroll
            for (int e = 0; e < 8; ++e) {
                int j = j0 + e;
                float f = (j == c) ? 0.f : lr[(j < c) ? j : (j - 1)];
                v[e] = (short)f2bf(f);
            }
        } else {
            #pragma unroll
            for (int e = 0; e < 8; ++e) {
                int j = j0 + e;
                v[e] = (short)f2bf(w1[o * 128 + j] * sc[j]);
            }
        }
        *(bf16x8*)(WB + idx) = v;
    } else {
        int o = threadIdx.x;
        if (o < 128) {
            float s = 0.f;
            for (int j = 0; j < 128; ++j) s += tr[j] * w1[o * 128 + j];
            bias[o] = s;
        }
    }
}

// ---- main GEMM: 256 WGs (64 M-tiles x 4 K-quarters), 512 thr = 8 waves (2M x 4N)
__global__ __launch_bounds__(512, 2) void lc_gemm(
    const float* __restrict__ x, const float* __restrict__ sc, const float* __restrict__ tr,
    const __hip_bfloat16* __restrict__ WB, float* __restrict__ parts)
{
    __shared__ float XT[IN * 128];    // XT[j][row ^ SWZ(j)] = x_scaled, 64 KB exactly

    const int tid = threadIdx.x;
    const int bid = blockIdx.x;
    const int mt  = bid >> 2;
    const int kq  = bid & 3;
    const int row0 = mt << 7;

    {   // stage + transpose + scale/translate
        const int jj  = (tid & 31) << 2;
        const int swz = SWZ(jj);
        const float4 s4 = *(const float4*)(sc + jj);
        const float4 t4 = *(const float4*)(tr + jj);
        const float i0 = 1.f / s4.x, i1 = 1.f / s4.y, i2 = 1.f / s4.z, i3 = 1.f / s4.w;
        const int rb0 = tid >> 5;
        #pragma unroll
        for (int it = 0; it < 8; ++it) {
            const int r = rb0 + (it << 4);
            const float4 xv = *(const float4*)(x + (size_t)(row0 + r) * IN + jj);
            const int rs = r ^ swz;
            XT[(jj + 0) * 128 + rs] = (xv.x - t4.x) * i0;
            XT[(jj + 1) * 128 + rs] = (xv.y - t4.y) * i1;
            XT[(jj + 2) * 128 + rs] = (xv.z - t4.z) * i2;
            XT[(jj + 3) * 128 + rs] = (xv.w - t4.w) * i3;
        }
    }
    __syncthreads();

    const int lane = tid & 63;
    const int wv = tid >> 6;
    const int wm = wv >> 2;       // 0..1 : 64-row half
    const int wn = wv & 3;        // 0..3 : 32-col group
    const int cl = lane & 15;
    const int kg = lane >> 4;

    // A fragments: constant for the whole kernel (bf16 of scaled x)
    bf16x8 a[4][4];
    #pragma unroll
    for (int rb = 0; rb < 4; ++rb) {
        const int row = wm * 64 + rb * 16 + cl;
        #pragma unroll
        for (int s = 0; s < 4; ++s) {
            const int j0 = s * 32 + kg * 8;
            bf16x8 av;
            #pragma unroll
            for (int e = 0; e < 8; ++e) {
                const int j = j0 + e;
                av[e] = (short)f2bf(XT[j * 128 + (row ^ SWZ(j))]);
            }
            a[rb][s] = av;
        }
    }

    const int c_lo = (kq == 0) ? 0 : (33 + (kq - 1) * 32);
    const int nc   = (kq == 0) ? 33 : 32;
    const __hip_bfloat16* wb = WB + (size_t)c_lo * WB_CHUNK + (size_t)(wn * 32 + cl) * IN + kg * 8;

    f32x4 y[4][2];
    #pragma unroll
    for (int rb = 0; rb < 4; ++rb)
        #pragma unroll
        for (int cb = 0; cb < 2; ++cb)
            y[rb][cb] = (f32x4){0.f, 0.f, 0.f, 0.f};

    bf16x8 B0[2][4], B1[2][4];

    auto loadB = [&](bf16x8 (&Bf)[2][4], int ci) {
        const __hip_bfloat16* p = wb + (size_t)ci * WB_CHUNK;
        #pragma unroll
        for (int cb = 0; cb < 2; ++cb)
            #pragma unroll
            for (int s = 0; s < 4; ++s)
                Bf[cb][s] = *(const bf16x8*)(p + cb * (16 * IN) + s * 32);
    };

    const f32x4 Zv = {0.f, 0.f, 0.f, 0.f};

    auto doChunk = [&](bf16x8 (&Bf)[2][4], int c) {
        f32x4 U[4][2];
        #pragma unroll
        for (int s = 0; s < 4; ++s)
            #pragma unroll
            for (int rb = 0; rb < 4; ++rb)
                #pragma unroll
                for (int cb = 0; cb < 2; ++cb)
                    U[rb][cb] = __builtin_amdgcn_mfma_f32_16x16x32_bf16(
                        a[rb][s], Bf[cb][s], (s == 0) ? Zv : U[rb][cb], 0, 0, 0);
        #pragma unroll
        for (int rb = 0; rb < 4; ++rb) {
            f32x4 xiv;
            if (c < 128) {
                const int rr = (wm * 64 + rb * 16 + kg * 4) ^ SWZ(c);
                xiv = *(const f32x4*)(&XT[c * 128 + rr]);
            } else {
                xiv = (f32x4){1.f, 1.f, 1.f, 1.f};
            }
            #pragma unroll
            for (int cb = 0; cb < 2; ++cb)
                #pragma unroll
                for (int q = 0; q < 4; ++q)
                    y[rb][cb][q] += xiv[q] * U[rb][cb][q];
        }
    };

    loadB(B0, 0);
    int ci = 0;
    for (;;) {
        if (ci + 1 < nc) loadB(B1, ci + 1);
        doChunk(B0, c_lo + ci);
        if (++ci >= nc) break;
        if (ci + 1 < nc) loadB(B0, ci + 1);
        doChunk(B1, c_lo + ci);
        if (++ci >= nc) break;
    }

    float* po = parts + (size_t)kq * ((size_t)NB * OUT);
    #pragma unroll
    for (int rb = 0; rb < 4; ++rb) {
        const int grow = row0 + wm * 64 + rb * 16 + kg * 4;
        #pragma unroll
        for (int cb = 0; cb < 2; ++cb) {
            const int col = wn * 32 + cb * 16 + cl;
            #pragma unroll
            for (int q = 0; q < 4; ++q)
                po[(size_t)(grow + q) * OUT + col] = y[rb][cb][q];
        }
    }
}

// ---- reduce split-K partials + bias, then LayerNorm(gamma, beta). One wave per row.
__global__ __launch_bounds__(256) void reduce_ln(
    const float* __restrict__ parts, const float* __restrict__ bias,
    const float* __restrict__ gamma, const float* __restrict__ beta,
    float* __restrict__ out)
{
    const int lane = threadIdx.x & 63;
    const int row  = blockIdx.x * 4 + (threadIdx.x >> 6);
    const int c0   = lane * 2;
    const size_t off = (size_t)row * OUT + c0;
    const size_t Q = (size_t)NB * OUT;

    float2 bb = *(const float2*)(bias + c0);
    float2 p0 = *(const float2*)(parts + off);
    float2 p1 = *(const float2*)(parts + Q + off);
    float2 p2 = *(const float2*)(parts + 2 * Q + off);
    float2 p3 = *(const float2*)(parts + 3 * Q + off);
    float y0 = bb.x + p0.x + p1.x + p2.x + p3.x;
    float y1 = bb.y + p0.y + p1.y + p2.y + p3.y;

    float s = y0 + y1, ss = y0 * y0 + y1 * y1;
    #pragma unroll
    for (int m = 1; m < 64; m <<= 1) {
        s  += __shfl_xor(s, m);
        ss += __shfl_xor(ss, m);
    }
    const float mu  = s * (1.f / 128.f);
    const float var = ss * (1.f / 128.f) - mu * mu;
    const float rs  = rsqrtf(var + 1e-5f);

    float2 gg = *(const float2*)(gamma + c0);
    float2 be = *(const float2*)(beta + c0);
    float2 o2 = { (y0 - mu) * rs * gg.x + be.x, (y1 - mu) * rs * gg.y + be.y };
    *(float2*)(out + off) = o2;
}

extern "C" void kernel_launch(void* const* d_in, const int* in_sizes, int n_in,
                              void* d_out, int out_size, void* d_ws, size_t ws_size,
                              hipStream_t stream) {
    const float* x     = (const float*)d_in[0];
    const float* sc    = (const float*)d_in[1];
    const float* tr    = (const float*)d_in[2];
    const float* lcw   = (const float*)d_in[3];
    const float* w1    = (const float*)d_in[4];
    const float* gamma = (const float*)d_in[5];
    const float* beta  = (const float*)d_in[6];
    float* out = (float*)d_out;

    char* ws = (char*)d_ws;
    __hip_bfloat16* WB = (__hip_bfloat16*)ws;                       // 129*128*128*2 = 4,227,072 B
    float* bias  = (float*)(ws + 4227072);                          // 512 B
    float* parts = (float*)(ws + 4227072 + 512);                    // 4 * 8192*128*4 = 16 MB

    prep_kernel<<<1033, 256, 0, stream>>>(lcw, w1, sc, tr, WB, bias);
    lc_gemm<<<256, 512, 0, stream>>>(x, sc, tr, WB, parts);
    reduce_ln<<<2048, 256, 0, stream>>>(parts, bias, gamma, beta, out);
}